// Round 4
// baseline (577.647 us; speedup 1.0000x reference)
//
#include <hip/hip_runtime.h>

#define N_NODES  50000
#define N_EDGES  600000
#define N_GRAPHS 512

static __device__ __forceinline__ float4 f4zero() { return make_float4(0.f, 0.f, 0.f, 0.f); }

// ---------------- tiny init kernels (avoid hipMemsetAsync under capture) ----

__global__ void zero_int_kernel(int* __restrict__ p, int n) {
    int i = blockIdx.x * blockDim.x + threadIdx.x;
    if (i < n) p[i] = 0;
}
__global__ void zero_float_kernel(float* __restrict__ p, int n) {
    int i = blockIdx.x * blockDim.x + threadIdx.x;
    if (i < n) p[i] = 0.f;
}

// ---------------- CSR build ----------------

__global__ void hist_kernel(const int* __restrict__ edge, int* __restrict__ rowptr) {
    int e = blockIdx.x * blockDim.x + threadIdx.x;
    if (e < N_EDGES) atomicAdd(&rowptr[edge[N_EDGES + e] + 1], 1);
}

// in-place inclusive scan of data[0..n-1], single block of 1024
__global__ void scan_kernel(int* __restrict__ data, int n) {
    const int T = 1024;
    __shared__ int sums[T];
    int t = threadIdx.x;
    int chunk = (n + T - 1) / T;
    int base = t * chunk;
    int s = 0;
    for (int j = 0; j < chunk; ++j) {
        int idx = base + j;
        if (idx < n) s += data[idx];
    }
    sums[t] = s;
    __syncthreads();
    for (int off = 1; off < T; off <<= 1) {
        int v = (t >= off) ? sums[t - off] : 0;
        __syncthreads();
        sums[t] += v;
        __syncthreads();
    }
    int run = sums[t] - s;  // exclusive prefix for this thread's chunk
    for (int j = 0; j < chunk; ++j) {
        int idx = base + j;
        if (idx < n) { run += data[idx]; data[idx] = run; }
    }
}

__global__ void cursor_kernel(const int* __restrict__ rowptr, int* __restrict__ cursor) {
    int i = blockIdx.x * blockDim.x + threadIdx.x;
    if (i < N_NODES) cursor[i] = rowptr[i];
}

__global__ void scatter_kernel(const int* __restrict__ edge, int* __restrict__ cursor,
                               int* __restrict__ csr) {
    int e = blockIdx.x * blockDim.x + threadIdx.x;
    if (e < N_EDGES) {
        int d = edge[N_EDGES + e];
        int p = atomicAdd(&cursor[d], 1);
        csr[p] = edge[e];
    }
}

// ---------------- edge aggregation (pull, no float atomics) ----------------

template <int F>
__global__ void aggregate_kernel(const float* __restrict__ X, const int* __restrict__ rowptr,
                                 const int* __restrict__ csr, float* __restrict__ OUT) {
    int i = blockIdx.x;   // node
    int f = threadIdx.x;  // feature (blockDim == F)
    int s = rowptr[i], e = rowptr[i + 1];
    float acc = 0.f;
    for (int p = s; p < e; ++p) {
        int j = csr[p];
        acc += X[(size_t)j * F + f];
    }
    OUT[(size_t)i * F + f] = acc;
}

// ---------------- fused node GEMM ----------------
// OUT[i][o] = act( sum_k A1[i,k]*W1[o,k] (+ sum_k A2[i,k]*W2[o,k]) (+ ADDIN[i,o]) (+ bias[o]) )
template <int K, int N, bool TWO, bool RELU, bool HASADD, bool HASBIAS>
__launch_bounds__(256)
__global__ void gemm_fused(const float* __restrict__ A1, const float* __restrict__ W1,
                           const float* __restrict__ A2, const float* __restrict__ W2,
                           const float* __restrict__ bias, const float* __restrict__ ADDIN,
                           float* __restrict__ OUT, int M) {
    constexpr int BM = 64, KC = 32, TM = 4, TN = N / 16;
    __shared__ float A1t[KC][BM];
    __shared__ float A2t[TWO ? KC : 1][TWO ? BM : 1];
    __shared__ float W1c[KC][N];
    __shared__ float W2c[TWO ? KC : 1][TWO ? N : 1];

    int tid = threadIdx.x;
    int colt = tid & 15, rowt = tid >> 4;
    int i0 = blockIdx.x * BM;

    float acc[TM][TN];
#pragma unroll
    for (int m = 0; m < TM; ++m)
#pragma unroll
        for (int n = 0; n < TN; ++n) acc[m][n] = 0.f;

    for (int c0 = 0; c0 < K; c0 += KC) {
        // stage A tile(s), transposed: A1t[k][row]
#pragma unroll
        for (int j = 0; j < (BM * KC / 4) / 256; ++j) {  // 2 iters
            int lin = tid + j * 256;
            int row = lin >> 3, k4 = (lin & 7) * 4;
            int gr = i0 + row;
            float4 v = f4zero();
            if (gr < M) v = *(const float4*)(A1 + (size_t)gr * K + c0 + k4);
            A1t[k4 + 0][row] = v.x; A1t[k4 + 1][row] = v.y;
            A1t[k4 + 2][row] = v.z; A1t[k4 + 3][row] = v.w;
            if constexpr (TWO) {
                float4 u = f4zero();
                if (gr < M) u = *(const float4*)(A2 + (size_t)gr * K + c0 + k4);
                A2t[k4 + 0][row] = u.x; A2t[k4 + 1][row] = u.y;
                A2t[k4 + 2][row] = u.z; A2t[k4 + 3][row] = u.w;
            }
        }
        // stage W chunk(s): W1c[k][o]
#pragma unroll
        for (int j = 0; j < (KC * N / 4) / 256; ++j) {
            int lin = tid + j * 256;
            int o = lin >> 3, k4 = (lin & 7) * 4;
            float4 v = *(const float4*)(W1 + (size_t)o * K + c0 + k4);
            W1c[k4 + 0][o] = v.x; W1c[k4 + 1][o] = v.y;
            W1c[k4 + 2][o] = v.z; W1c[k4 + 3][o] = v.w;
            if constexpr (TWO) {
                float4 u = *(const float4*)(W2 + (size_t)o * K + c0 + k4);
                W2c[k4 + 0][o] = u.x; W2c[k4 + 1][o] = u.y;
                W2c[k4 + 2][o] = u.z; W2c[k4 + 3][o] = u.w;
            }
        }
        __syncthreads();
#pragma unroll
        for (int k = 0; k < KC; ++k) {
            float a1[TM];
            *(float4*)a1 = *(const float4*)&A1t[k][rowt * TM];
            float w1[TN];
#pragma unroll
            for (int n4 = 0; n4 < TN; n4 += 4)
                *(float4*)&w1[n4] = *(const float4*)&W1c[k][colt * TN + n4];
#pragma unroll
            for (int m = 0; m < TM; ++m)
#pragma unroll
                for (int n = 0; n < TN; ++n) acc[m][n] += a1[m] * w1[n];
            if constexpr (TWO) {
                float a2[TM];
                *(float4*)a2 = *(const float4*)&A2t[k][rowt * TM];
                float w2[TN];
#pragma unroll
                for (int n4 = 0; n4 < TN; n4 += 4)
                    *(float4*)&w2[n4] = *(const float4*)&W2c[k][colt * TN + n4];
#pragma unroll
                for (int m = 0; m < TM; ++m)
#pragma unroll
                    for (int n = 0; n < TN; ++n) acc[m][n] += a2[m] * w2[n];
            }
        }
        __syncthreads();
    }
    // epilogue
#pragma unroll
    for (int m = 0; m < TM; ++m) {
        int gr = i0 + rowt * TM + m;
        if (gr >= M) continue;
#pragma unroll
        for (int n4 = 0; n4 < TN; n4 += 4) {
            int col = colt * TN + n4;
            float4 v = make_float4(acc[m][n4], acc[m][n4 + 1], acc[m][n4 + 2], acc[m][n4 + 3]);
            if constexpr (HASBIAS) {
                float4 b = *(const float4*)(bias + col);
                v.x += b.x; v.y += b.y; v.z += b.z; v.w += b.w;
            }
            if constexpr (HASADD) {
                float4 a = *(const float4*)(ADDIN + (size_t)gr * N + col);
                v.x += a.x; v.y += a.y; v.z += a.z; v.w += a.w;
            }
            if constexpr (RELU) {
                v.x = fmaxf(v.x, 0.f); v.y = fmaxf(v.y, 0.f);
                v.z = fmaxf(v.z, 0.f); v.w = fmaxf(v.w, 0.f);
            }
            *(float4*)(OUT + (size_t)gr * N + col) = v;
        }
    }
}

// ---------------- pooling (batch is sorted) ----------------

__global__ void pool_kernel(const float* __restrict__ H, const int* __restrict__ batch,
                            float* __restrict__ G, int n) {
    const int CHUNK = 128;
    int f = threadIdx.x;  // 64 threads
    int start = blockIdx.x * CHUNK;
    if (start >= n) return;
    int end = start + CHUNK; if (end > n) end = n;
    int cur = batch[start];
    float acc = 0.f;
    for (int i = start; i < end; ++i) {
        int b = batch[i];
        if (b != cur) { atomicAdd(&G[(size_t)cur * 64 + f], acc); acc = 0.f; cur = b; }
        acc += H[(size_t)i * 64 + f];
    }
    atomicAdd(&G[(size_t)cur * 64 + f], acc);
}

// ---------------- MLP head + log_softmax ----------------

__global__ void mlp_head(const float* __restrict__ G, const float* __restrict__ fc1w,
                         const float* __restrict__ fc1b, const float* __restrict__ fc2w,
                         const float* __restrict__ fc2b, float* __restrict__ out) {
    int g = blockIdx.x;
    int t = threadIdx.x;  // 64
    __shared__ float gr[64], tt[64], sc[32], red[2];
    gr[t] = G[(size_t)g * 64 + t];
    __syncthreads();
    float acc = fc1b[t];
#pragma unroll
    for (int k = 0; k < 64; ++k) acc += gr[k] * fc1w[t * 64 + k];
    tt[t] = fmaxf(acc, 0.f);
    __syncthreads();
    if (t < 32) {
        float s = fc2b[t];
#pragma unroll
        for (int k = 0; k < 64; ++k) s += tt[k] * fc2w[t * 64 + k];
        sc[t] = s;
    }
    __syncthreads();
    if (t == 0) {
        float mx = sc[0];
        for (int c = 1; c < 32; ++c) mx = fmaxf(mx, sc[c]);
        float sum = 0.f;
        for (int c = 0; c < 32; ++c) sum += expf(sc[c] - mx);
        red[0] = mx; red[1] = logf(sum);
    }
    __syncthreads();
    if (t < 32) out[(size_t)g * 32 + t] = sc[t] - red[0] - red[1];
}

// ---------------- launch ----------------

extern "C" void kernel_launch(void* const* d_in, const int* in_sizes, int n_in,
                              void* d_out, int out_size, void* d_ws, size_t ws_size,
                              hipStream_t stream) {
    const float* x       = (const float*)d_in[0];
    const int*   edge    = (const int*)d_in[1];   // [2][E]: row0=src, row1=dst
    const int*   batch   = (const int*)d_in[2];
    const float* w1_rel  = (const float*)d_in[3];
    const float* b1      = (const float*)d_in[4];
    const float* w1_root = (const float*)d_in[5];
    const float* w2_rel  = (const float*)d_in[6];
    const float* b2      = (const float*)d_in[7];
    const float* w2_root = (const float*)d_in[8];
    const float* w3_rel  = (const float*)d_in[9];
    const float* b3      = (const float*)d_in[10];
    const float* w3_root = (const float*)d_in[11];
    const float* fc1w    = (const float*)d_in[12];
    const float* fc1b    = (const float*)d_in[13];
    const float* fc2w    = (const float*)d_in[14];
    const float* fc2b    = (const float*)d_in[15];
    float* out = (float*)d_out;

    char* p = (char*)d_ws;
    size_t used = 0;
    auto alloc = [&](size_t bytes) {
        char* r = p + used;
        used += (bytes + 255) & ~(size_t)255;
        return r;
    };
    int*   rowptr = (int*)alloc((N_NODES + 1) * sizeof(int));
    int*   cursor = (int*)alloc(N_NODES * sizeof(int));
    int*   csr    = (int*)alloc(N_EDGES * sizeof(int));
    // Two big 25.6MB regions; 64-wide temporaries alias into them once the
    // 128-wide tenants are dead.  Peak d_ws use ≈ 54 MB.
    float* A      = (float*)alloc((size_t)N_NODES * 128 * sizeof(float));  // aggr1; later C|D
    float* B      = (float*)alloc((size_t)N_NODES * 128 * sizeof(float));  // h1;    later E
    float* G      = (float*)alloc((size_t)N_GRAPHS * 64 * sizeof(float));

    // Workspace guard: if the harness gave us less scratch than needed, bail
    // out cleanly (wrong answer, but no wild device writes / container death).
    if (used > ws_size) return;

    float* C = A;                         // [N,64]  y2 / h2
    float* D = A + (size_t)N_NODES * 64;  // [N,64]  aggr2 / y3 / h3
    float* E = B;                         // [N,64]  aggr3 (h1 dead by then)

    // CSR build (shared by all 3 layers)
    zero_int_kernel<<<(N_NODES + 256) / 256, 256, 0, stream>>>(rowptr, N_NODES + 1);
    hist_kernel<<<(N_EDGES + 255) / 256, 256, 0, stream>>>(edge, rowptr);
    scan_kernel<<<1, 1024, 0, stream>>>(rowptr, N_NODES + 1);
    cursor_kernel<<<(N_NODES + 255) / 256, 256, 0, stream>>>(rowptr, cursor);
    scatter_kernel<<<(N_EDGES + 255) / 256, 256, 0, stream>>>(edge, cursor, csr);

    int gblk = (N_NODES + 63) / 64;

    // Layer 1: aggr1 = segsum(x); h1 = relu(aggr1@w1_rel.T + x@w1_root.T + b1)
    aggregate_kernel<128><<<N_NODES, 128, 0, stream>>>(x, rowptr, csr, A);
    gemm_fused<128, 128, true, true, false, true>
        <<<gblk, 256, 0, stream>>>(A, w1_rel, x, w1_root, b1, nullptr, B, N_NODES);

    // Layer 2 (transform-first): y2 = h1@w2_rel.T; aggr2 = segsum(y2);
    // h2 = relu(aggr2 + h1@w2_root.T + b2)
    gemm_fused<128, 64, false, false, false, false>
        <<<gblk, 256, 0, stream>>>(B, w2_rel, nullptr, nullptr, nullptr, nullptr, C, N_NODES);
    aggregate_kernel<64><<<N_NODES, 64, 0, stream>>>(C, rowptr, csr, D);
    gemm_fused<128, 64, false, true, true, true>
        <<<gblk, 256, 0, stream>>>(B, w2_root, nullptr, nullptr, b2, D, C, N_NODES);

    // Layer 3: y3 = h2@w3_rel.T; aggr3 = segsum(y3); h3 = aggr3 + h2@w3_root.T + b3
    gemm_fused<64, 64, false, false, false, false>
        <<<gblk, 256, 0, stream>>>(C, w3_rel, nullptr, nullptr, nullptr, nullptr, D, N_NODES);
    aggregate_kernel<64><<<N_NODES, 64, 0, stream>>>(D, rowptr, csr, E);
    gemm_fused<64, 64, false, false, true, true>
        <<<gblk, 256, 0, stream>>>(C, w3_root, nullptr, nullptr, b3, E, D, N_NODES);

    // Pool + head
    zero_float_kernel<<<(N_GRAPHS * 64 + 255) / 256, 256, 0, stream>>>(G, N_GRAPHS * 64);
    pool_kernel<<<(N_NODES + 127) / 128, 64, 0, stream>>>(D, batch, G, N_NODES);
    mlp_head<<<N_GRAPHS, 64, 0, stream>>>(G, fc1w, fc1b, fc2w, fc2b, out);
}